// Round 1
// baseline (207.386 us; speedup 1.0000x reference)
//
#include <hip/hip_runtime.h>

// Problem constants: B=8, N=7, C=64, H=128, W=128
#define NB     8
#define NN     7
#define D_EL   (64*128*128)       // 1048576 floats per (b,n)
#define DV     (D_EL/4)           // 262144 float4 per (b,n)
#define NPAIR  28                 // unique (i<=j) pairs of 7
#define BPB    256                // blocks per batch (gram partials)
#define BPB3   256                // blocks per batch (apply)
#define THREADS 256

__device__ __forceinline__ int pair_idx(int i, int j) {
    // i <= j, row-major triangular packing matching the accumulation order
    return i * 7 - (i * (i - 1)) / 2 + (j - i);
}

// ---------------------------------------------------------------------------
// Kernel 1: per-block partial Gram sums.  grid = NB*BPB blocks.
// partials[block*28 + k] = partial sum of v_i . v_j for pair k.
// ---------------------------------------------------------------------------
__global__ __launch_bounds__(THREADS)
void gram_partial(const float* __restrict__ x2, float* __restrict__ partials) {
    const int b   = blockIdx.x / BPB;
    const int blk = blockIdx.x % BPB;
    const float4* base = (const float4*)(x2 + (size_t)b * NN * D_EL);

    float acc[NPAIR];
#pragma unroll
    for (int k = 0; k < NPAIR; ++k) acc[k] = 0.f;

    for (int p = blk * THREADS + threadIdx.x; p < DV; p += BPB * THREADS) {
        float4 v[NN];
#pragma unroll
        for (int n = 0; n < NN; ++n) v[n] = base[(size_t)n * DV + p];
        int k = 0;
#pragma unroll
        for (int i = 0; i < NN; ++i)
#pragma unroll
            for (int j = i; j < NN; ++j, ++k) {
                acc[k] = fmaf(v[i].x, v[j].x, acc[k]);
                acc[k] = fmaf(v[i].y, v[j].y, acc[k]);
                acc[k] = fmaf(v[i].z, v[j].z, acc[k]);
                acc[k] = fmaf(v[i].w, v[j].w, acc[k]);
            }
    }

    // block reduce: wave shuffle then LDS across the 4 waves
    __shared__ float lds[4][NPAIR];
    const int lane = threadIdx.x & 63;
    const int wid  = threadIdx.x >> 6;
#pragma unroll
    for (int k = 0; k < NPAIR; ++k) {
        float s = acc[k];
#pragma unroll
        for (int o = 32; o > 0; o >>= 1) s += __shfl_down(s, o, 64);
        if (lane == 0) lds[wid][k] = s;
    }
    __syncthreads();
    if (threadIdx.x < NPAIR) {
        float s = lds[0][threadIdx.x] + lds[1][threadIdx.x]
                + lds[2][threadIdx.x] + lds[3][threadIdx.x];
        partials[(size_t)blockIdx.x * NPAIR + threadIdx.x] = s;
    }
}

// ---------------------------------------------------------------------------
// Kernel 2: reduce partials -> energy (7x7, symmetric) -> attention (softmax).
// grid = NB blocks.  softmax(rowmax(E)-E) == softmax(-E)  (shift-invariant).
// ---------------------------------------------------------------------------
__global__ __launch_bounds__(THREADS)
void softmax_k(const float* __restrict__ partials, float* __restrict__ att) {
    const int b = blockIdx.x;
    const float* pb = partials + (size_t)b * BPB * NPAIR;

    float acc[NPAIR];
#pragma unroll
    for (int k = 0; k < NPAIR; ++k) acc[k] = pb[(size_t)threadIdx.x * NPAIR + k];

    __shared__ float lds[4][NPAIR];
    __shared__ float e_s[NPAIR];
    const int lane = threadIdx.x & 63;
    const int wid  = threadIdx.x >> 6;
#pragma unroll
    for (int k = 0; k < NPAIR; ++k) {
        float s = acc[k];
#pragma unroll
        for (int o = 32; o > 0; o >>= 1) s += __shfl_down(s, o, 64);
        if (lane == 0) lds[wid][k] = s;
    }
    __syncthreads();
    if (threadIdx.x < NPAIR) {
        e_s[threadIdx.x] = lds[0][threadIdx.x] + lds[1][threadIdx.x]
                         + lds[2][threadIdx.x] + lds[3][threadIdx.x];
    }
    __syncthreads();

    if (threadIdx.x < NN) {
        const int n = threadIdx.x;
        float z[NN];
#pragma unroll
        for (int m = 0; m < NN; ++m) {
            const int i = n < m ? n : m;
            const int j = n < m ? m : n;
            z[m] = -e_s[pair_idx(i, j)];
        }
        float mx = z[0];
#pragma unroll
        for (int m = 1; m < NN; ++m) mx = fmaxf(mx, z[m]);
        float p[NN], s = 0.f;
#pragma unroll
        for (int m = 0; m < NN; ++m) { p[m] = expf(z[m] - mx); s += p[m]; }
        const float inv = 1.f / s;
#pragma unroll
        for (int m = 0; m < NN; ++m)
            att[(size_t)b * NN * NN + n * NN + m] = p[m] * inv;
    }
}

// ---------------------------------------------------------------------------
// Kernel 3: out[b,n,d] = x1 * (1 + gamma * sum_m att[n,m] * x2[b,m,d])
// grid = NB*BPB3 blocks.  Reads x2 once per position (reused for all 7 n).
// ---------------------------------------------------------------------------
__global__ __launch_bounds__(THREADS)
void apply_k(const float* __restrict__ x1, const float* __restrict__ x2,
             const float* __restrict__ att, const float* __restrict__ gamma,
             float* __restrict__ out) {
    const int b   = blockIdx.x / BPB3;
    const int blk = blockIdx.x % BPB3;

    __shared__ float a_s[NN * NN];
    if (threadIdx.x < NN * NN)
        a_s[threadIdx.x] = att[(size_t)b * NN * NN + threadIdx.x];
    __syncthreads();

    const float g = gamma[0];
    const float4* v2 = (const float4*)(x2 + (size_t)b * NN * D_EL);
    const float4* v1 = (const float4*)(x1 + (size_t)b * NN * D_EL);
    float4*       vo = (float4*)((float*)out + (size_t)b * NN * D_EL);

    for (int p = blk * THREADS + threadIdx.x; p < DV; p += BPB3 * THREADS) {
        float4 v[NN];
#pragma unroll
        for (int m = 0; m < NN; ++m) v[m] = v2[(size_t)m * DV + p];
#pragma unroll
        for (int n = 0; n < NN; ++n) {
            float4 o = make_float4(0.f, 0.f, 0.f, 0.f);
#pragma unroll
            for (int m = 0; m < NN; ++m) {
                const float a = a_s[n * NN + m];
                o.x = fmaf(a, v[m].x, o.x);
                o.y = fmaf(a, v[m].y, o.y);
                o.z = fmaf(a, v[m].z, o.z);
                o.w = fmaf(a, v[m].w, o.w);
            }
            const float4 x = v1[(size_t)n * DV + p];
            float4 r;
            r.x = fmaf(x.x, g * o.x, x.x);
            r.y = fmaf(x.y, g * o.y, x.y);
            r.z = fmaf(x.z, g * o.z, x.z);
            r.w = fmaf(x.w, g * o.w, x.w);
            vo[(size_t)n * DV + p] = r;
        }
    }
}

extern "C" void kernel_launch(void* const* d_in, const int* in_sizes, int n_in,
                              void* d_out, int out_size, void* d_ws, size_t ws_size,
                              hipStream_t stream) {
    const float* x1    = (const float*)d_in[0];
    const float* x2    = (const float*)d_in[1];
    const float* gamma = (const float*)d_in[2];
    float*       out   = (float*)d_out;

    float* partials = (float*)d_ws;                         // NB*BPB*NPAIR floats
    float* att      = partials + (size_t)NB * BPB * NPAIR;  // NB*49 floats

    gram_partial<<<dim3(NB * BPB),  dim3(THREADS), 0, stream>>>(x2, partials);
    softmax_k  <<<dim3(NB),         dim3(THREADS), 0, stream>>>(partials, att);
    apply_k    <<<dim3(NB * BPB3),  dim3(THREADS), 0, stream>>>(x1, x2, att, gamma, out);
}